// Round 1
// baseline (53237.109 us; speedup 1.0000x reference)
//
#include <hip/hip_runtime.h>
#include <hip/hip_bf16.h>
#include <math.h>

#define V    50257
#define E    512
#define H    1024
#define S    128
#define BS   8
#define T    64
#define SOS  1
#define EOS  2
#define NEGV (-1e9f)
#define H3   (3*H)
#define KS   8            // k-splits for GRU partials
#define RPK  ((E+H)/KS)   // 192 combined rows per split

// ---------------- init ----------------
__global__ void k_init(const float* __restrict__ h0, float* h, float* cum,
                       int* len, int* fin, int* lat, int* tok) {
    int t = threadIdx.x;
    for (int i = t; i < BS*H; i += 256) h[i] = h0[i % H];
    for (int i = t; i < BS*T; i += 256) tok[i] = 0;
    if (t < BS) { cum[t] = 0.f; len[t] = 1; fin[t] = 0; lat[t] = SOS; }
}

// ---------------- GRU partials (split-K, deterministic) ----------------
// part[((k*4+g)*8 + b)*H + j], g: 0=z(combined) 1=r(combined) 2=n_x 3=n_h
__global__ __launch_bounds__(256) void k_gru_part(
    const float* __restrict__ emb, const float* __restrict__ Wx,
    const float* __restrict__ Wh, const float* __restrict__ h,
    const int* __restrict__ lat, float* __restrict__ part)
{
    int jb = blockIdx.x;        // 0..3
    int k  = blockIdx.y;        // 0..KS-1
    int t  = threadIdx.x;
    int j  = jb*256 + t;
    int c0 = k * RPK;
    __shared__ float vals[RPK*BS];
    for (int m = t; m < RPK*BS; m += 256) {
        int c = c0 + (m >> 3);
        int b = m & 7;
        float v;
        if (c < E) v = emb[(size_t)lat[b]*E + c];
        else       v = h[b*H + (c - E)];
        vals[m] = v;
    }
    __syncthreads();
    float pz[BS] = {0}, pr[BS] = {0}, pnx[BS] = {0}, pnh[BS] = {0};
    for (int cc = 0; cc < RPK; ++cc) {
        int c = c0 + cc;
        bool isx = (c < E);
        const float* Wrow = isx ? (Wx + (size_t)c*H3) : (Wh + (size_t)(c-E)*H3);
        float wz = Wrow[j];
        float wr = Wrow[j + H];
        float wn = Wrow[j + 2*H];
        #pragma unroll
        for (int b = 0; b < BS; ++b) {
            float v = vals[cc*8 + b];
            pz[b] += v * wz;
            pr[b] += v * wr;
            if (isx) pnx[b] += v * wn; else pnh[b] += v * wn;
        }
    }
    #pragma unroll
    for (int b = 0; b < BS; ++b) {
        part[(((size_t)k*4 + 0)*8 + b)*H + j] = pz[b];
        part[(((size_t)k*4 + 1)*8 + b)*H + j] = pr[b];
        part[(((size_t)k*4 + 2)*8 + b)*H + j] = pnx[b];
        part[(((size_t)k*4 + 3)*8 + b)*H + j] = pnh[b];
    }
}

// ---------------- GRU gates -> h_new into hcT[i][b] ----------------
__global__ __launch_bounds__(256) void k_gru_gate(
    const float* __restrict__ part, const float* __restrict__ h,
    float* __restrict__ hcT)
{
    int j = blockIdx.x*256 + threadIdx.x;
    #pragma unroll
    for (int b = 0; b < BS; ++b) {
        float pz = 0.f, pr = 0.f, pnx = 0.f, pnh = 0.f;
        for (int k = 0; k < KS; ++k) {
            pz  += part[(((size_t)k*4 + 0)*8 + b)*H + j];
            pr  += part[(((size_t)k*4 + 1)*8 + b)*H + j];
            pnx += part[(((size_t)k*4 + 2)*8 + b)*H + j];
            pnh += part[(((size_t)k*4 + 3)*8 + b)*H + j];
        }
        float z = 1.f / (1.f + expf(-pz));
        float r = 1.f / (1.f + expf(-pr));
        float n = tanhf(pnx + r * pnh);
        float hn = (1.f - z) * n + z * h[b*H + j];
        hcT[(size_t)j*8 + b] = hn;
    }
}

// ---------------- attention: scores -> softmax -> ctx ----------------
__global__ __launch_bounds__(256) void k_attn(
    const float* __restrict__ enc, float* __restrict__ hcT)
{
    int b = blockIdx.x;
    int t = threadIdx.x;
    __shared__ float hn[H];
    __shared__ float att[S];
    __shared__ float smax, ssum;
    for (int j = t; j < H; j += 256) hn[j] = hcT[(size_t)j*8 + b];
    __syncthreads();
    int wave = t >> 6, lane = t & 63;
    for (int s = wave; s < S; s += 4) {
        float acc = 0.f;
        for (int hh = lane; hh < H; hh += 64)
            acc += hn[hh] * enc[(size_t)s*H + hh];
        #pragma unroll
        for (int off = 32; off; off >>= 1) acc += __shfl_down(acc, off, 64);
        if (lane == 0) att[s] = acc;
    }
    __syncthreads();
    if (t == 0) {
        float m = -3.0e38f;
        for (int s = 0; s < S; ++s) m = fmaxf(m, att[s]);
        smax = m;
    }
    __syncthreads();
    if (t < S) att[t] = expf(att[t] - smax);
    __syncthreads();
    if (t == 0) {
        float sum = 0.f;
        for (int s = 0; s < S; ++s) sum += att[s];
        ssum = sum;
    }
    __syncthreads();
    if (t < S) att[t] = att[t] / ssum;
    __syncthreads();
    for (int j = t; j < H; j += 256) {
        float acc = 0.f;
        for (int s = 0; s < S; ++s) acc += att[s] * enc[(size_t)s*H + j];
        hcT[(size_t)(H + j)*8 + b] = acc;
    }
}

// ---------------- big GEMV: logits[b][v] = hc[b] . W_out[:,v] + b_out[v] ----------------
__global__ __launch_bounds__(256) void k_logits(
    const float* __restrict__ Wout, const float* __restrict__ bout,
    const float* __restrict__ hcT, float* __restrict__ logits)
{
    int v = blockIdx.x*256 + threadIdx.x;
    __shared__ float tile[256*8];
    float acc[BS];
    float bv = (v < V) ? bout[v] : 0.f;
    #pragma unroll
    for (int b = 0; b < BS; ++b) acc[b] = bv;
    for (int i0 = 0; i0 < 2*H; i0 += 256) {
        __syncthreads();
        for (int m = threadIdx.x; m < 256*8; m += 256)
            tile[m] = hcT[(size_t)i0*8 + m];
        __syncthreads();
        for (int ii = 0; ii < 256; ++ii) {
            float w = (v < V) ? Wout[(size_t)(i0+ii)*V + v] : 0.f;
            float4 a0 = *(const float4*)(tile + ii*8);
            float4 a1 = *(const float4*)(tile + ii*8 + 4);
            acc[0] += a0.x*w; acc[1] += a0.y*w; acc[2] += a0.z*w; acc[3] += a0.w*w;
            acc[4] += a1.x*w; acc[5] += a1.y*w; acc[6] += a1.z*w; acc[7] += a1.w*w;
        }
    }
    if (v < V) {
        #pragma unroll
        for (int b = 0; b < BS; ++b) logits[(size_t)b*V + v] = acc[b];
    }
}

// ---------------- per-beam exact top-8 + logsumexp ----------------
__global__ __launch_bounds__(256) void k_topk(
    const float* __restrict__ logits, float* __restrict__ t8v,
    int* __restrict__ t8i, float* __restrict__ lse)
{
    int b = blockIdx.x, t = threadIdx.x;
    const float* lg = logits + (size_t)b*V;
    float bv[8]; int bi[8];
    #pragma unroll
    for (int r = 0; r < 8; ++r) { bv[r] = -3.0e38f; bi[r] = 0x7fffffff; }
    float m = -3.0e38f, l = 0.f;
    for (int v = t; v < V; v += 256) {
        float x = lg[v];
        if (x > m) { l = l * expf(m - x) + 1.f; m = x; }
        else         l += expf(x - m);
        if (x > bv[7]) {
            bv[7] = x; bi[7] = v;
            #pragma unroll
            for (int q = 7; q > 0; --q) {
                if (bv[q] > bv[q-1]) {
                    float tv = bv[q]; bv[q] = bv[q-1]; bv[q-1] = tv;
                    int   ti = bi[q]; bi[q] = bi[q-1]; bi[q-1] = ti;
                }
            }
        }
    }
    __shared__ float pm[256], pl[256];
    pm[t] = m; pl[t] = l;
    __syncthreads();
    for (int off = 128; off; off >>= 1) {
        if (t < off) {
            float m2 = pm[t+off], l2 = pl[t+off];
            float M = fmaxf(pm[t], m2);
            pl[t] = pl[t]*expf(pm[t]-M) + l2*expf(m2-M);
            pm[t] = M;
        }
        __syncthreads();
    }
    if (t == 0) lse[b] = pm[0] + logf(pl[0]);

    __shared__ float pv[2048];
    __shared__ int   pi[2048];
    __shared__ float rv[256];
    __shared__ int   ri[256], rp[256];
    #pragma unroll
    for (int r = 0; r < 8; ++r) { pv[t*8+r] = bv[r]; pi[t*8+r] = bi[r]; }
    __syncthreads();
    for (int round = 0; round < 8; ++round) {
        float lv = -3.0e38f; int li = 0x7fffffff, lp = -1;
        #pragma unroll
        for (int r = 0; r < 8; ++r) {
            float v2 = pv[t*8+r]; int i2 = pi[t*8+r];
            if (v2 > lv || (v2 == lv && i2 < li)) { lv = v2; li = i2; lp = t*8+r; }
        }
        rv[t] = lv; ri[t] = li; rp[t] = lp;
        __syncthreads();
        for (int off = 128; off; off >>= 1) {
            if (t < off) {
                if (rv[t+off] > rv[t] || (rv[t+off] == rv[t] && ri[t+off] < ri[t])) {
                    rv[t] = rv[t+off]; ri[t] = ri[t+off]; rp[t] = rp[t+off];
                }
            }
            __syncthreads();
        }
        if (t == 0) {
            t8v[b*8 + round] = rv[0];
            t8i[b*8 + round] = ri[0];
            pv[rp[0]] = -3.0e38f; pi[rp[0]] = 0x7fffffff;
        }
        __syncthreads();
    }
}

// ---------------- beam update (exact reference semantics) ----------------
__global__ __launch_bounds__(256) void k_update(
    const float* __restrict__ t8v, const int* __restrict__ t8i,
    const float* __restrict__ lse,
    const float* cum_i, const int* len_i, const int* fin_i,
    const int* lat_i, const int* tok_i,
    float* cum_o, int* len_o, int* fin_o, int* lat_o, int* tok_o,
    const float* __restrict__ hcT, float* __restrict__ h, int step)
{
    int t = threadIdx.x;
    __shared__ float flat[64];
    __shared__ float ccum[64];
    __shared__ int   clen[64];
    __shared__ int   sel[8];
    if (t < 64) {
        int b = t >> 3, j = t & 7;
        int alive = fin_i[b] ? 0 : 1;
        float lp = t8v[b*8 + j] - lse[b];
        float cc = cum_i[b] + (alive ? lp : 0.f);
        int   cl = len_i[b] + alive;
        float score = cc / (float)cl;
        bool valid = (alive || j == 0) && ((step > 0) || (b == 0));
        flat[t] = valid ? score : NEGV;
        ccum[t] = cc; clen[t] = cl;
    }
    __syncthreads();
    if (t == 0) {
        bool taken[64];
        for (int i = 0; i < 64; ++i) taken[i] = false;
        for (int r = 0; r < 8; ++r) {
            float bestv = -3.4e38f; int bidx = 0;
            for (int i = 0; i < 64; ++i) {
                if (!taken[i] && flat[i] > bestv) { bestv = flat[i]; bidx = i; }
            }
            taken[bidx] = true; sel[r] = bidx;
        }
    }
    __syncthreads();
    if (t < 8) {
        int idx = sel[t];
        int parent = idx >> 3, child = idx & 7;
        int p_fin = fin_i[parent];
        int new_tok = t8i[parent*8 + child];
        cum_o[t] = ccum[idx];
        len_o[t] = clen[idx];
        fin_o[t] = (p_fin || new_tok == EOS) ? 1 : 0;
        lat_o[t] = p_fin ? lat_i[parent] : new_tok;
    }
    __syncthreads();
    for (int m = t; m < BS*T; m += 256) {
        int nb = m / T, pos = m % T;
        int idx = sel[nb];
        int parent = idx >> 3, child = idx & 7;
        int p_fin = fin_i[parent];
        int p_len = len_i[parent];
        int new_tok = t8i[parent*8 + child];
        int val = tok_i[parent*T + pos];
        if (pos == p_len - 1 && !p_fin) val = new_tok;
        tok_o[m] = val;
    }
    for (int m = t; m < BS*H; m += 256) {
        int nb = m / H, j = m % H;
        int parent = sel[nb] >> 3;
        h[m] = hcT[(size_t)j*8 + parent];
    }
}

// ---------------- finalize ----------------
__global__ void k_final(const float* cum, const int* len, const int* fin,
                        const int* tok, float* out)
{
    int t = threadIdx.x;
    __shared__ int bestIdx;
    if (t == 0) {
        bool anyf = false;
        for (int b = 0; b < BS; ++b) anyf = anyf || (fin[b] != 0);
        float bestv = -3.4e38f; int bi_ = 0;
        for (int b = 0; b < BS; ++b) {
            float sc = cum[b] / (float)len[b];
            float adj = anyf ? (fin[b] ? sc : NEGV) : sc;
            if (adj > bestv) { bestv = adj; bi_ = b; }
        }
        bestIdx = bi_;
        out[T] = cum[bi_] / (float)len[bi_];
    }
    __syncthreads();
    if (t < T) out[t] = (float)tok[bestIdx*T + t];
}

extern "C" void kernel_launch(void* const* d_in, const int* in_sizes, int n_in,
                              void* d_out, int out_size, void* d_ws, size_t ws_size,
                              hipStream_t stream) {
    const float* emb  = (const float*)d_in[0];
    const float* Wx   = (const float*)d_in[1];
    const float* Wh   = (const float*)d_in[2];
    const float* Wout = (const float*)d_in[3];
    const float* bout = (const float*)d_in[4];
    const float* enc  = (const float*)d_in[5];
    const float* h0   = (const float*)d_in[6];
    float* out = (float*)d_out;

    char* w = (char*)d_ws;
    float* h      = (float*)w;  w += (size_t)BS*H*4;
    float* hcT    = (float*)w;  w += (size_t)2*H*BS*4;
    float* part   = (float*)w;  w += (size_t)KS*4*BS*H*4;
    float* logits = (float*)w;  w += (size_t)BS*V*4;
    float* t8v    = (float*)w;  w += 64*4;
    float* lse    = (float*)w;  w += 8*4;
    float* cumb0  = (float*)w;  w += 8*4;
    float* cumb1  = (float*)w;  w += 8*4;
    int* lenb0 = (int*)w; w += 8*4;
    int* lenb1 = (int*)w; w += 8*4;
    int* finb0 = (int*)w; w += 8*4;
    int* finb1 = (int*)w; w += 8*4;
    int* latb0 = (int*)w; w += 8*4;
    int* latb1 = (int*)w; w += 8*4;
    int* tokb0 = (int*)w; w += (size_t)BS*T*4;
    int* tokb1 = (int*)w; w += (size_t)BS*T*4;
    int* t8i   = (int*)w; w += 64*4;

    float* cumb[2] = {cumb0, cumb1};
    int*   lenb[2] = {lenb0, lenb1};
    int*   finb[2] = {finb0, finb1};
    int*   latb[2] = {latb0, latb1};
    int*   tokb[2] = {tokb0, tokb1};

    k_init<<<1, 256, 0, stream>>>(h0, h, cumb[0], lenb[0], finb[0], latb[0], tokb[0]);

    for (int s = 0; s < T; ++s) {
        int p = s & 1, q = 1 - p;
        k_gru_part<<<dim3(4, KS), 256, 0, stream>>>(emb, Wx, Wh, h, latb[p], part);
        k_gru_gate<<<4, 256, 0, stream>>>(part, h, hcT);
        k_attn<<<BS, 256, 0, stream>>>(enc, hcT);
        k_logits<<<(V + 255) / 256, 256, 0, stream>>>(Wout, bout, hcT, logits);
        k_topk<<<BS, 256, 0, stream>>>(logits, t8v, t8i, lse);
        k_update<<<1, 256, 0, stream>>>(t8v, t8i, lse,
                                        cumb[p], lenb[p], finb[p], latb[p], tokb[p],
                                        cumb[q], lenb[q], finb[q], latb[q], tokb[q],
                                        hcT, h, s);
    }
    k_final<<<1, 64, 0, stream>>>(cumb[0], lenb[0], finb[0], tokb[0], out);
}